// Round 6
// baseline (254.995 us; speedup 1.0000x reference)
//
#include <hip/hip_runtime.h>
#include <math.h>

#define NLAB 8
#define BATCH 16
// acc layout per batch (floats):
//   [0..27]  emb sums, labels 1..7 x 4 ch
//   [28..34] cnt_k, labels 1..7
//   [35..40] cnt_i, labels 2..7
//   [41..46] agg sums, labels 2..7
#define S_OFF  0
#define CK_OFF 28
#define CI_OFF 35
#define AG_OFF 41
#define ACC_PER_B 48
#define ACC_FLOATS (BATCH * ACC_PER_B)
#define LAB_OFFSET 4096              // label byte-cache starts here in d_ws
#define GX 128                       // 128x16 = 2048 blocks = exactly 8/CU @ (256,8)
#define ILP 4

typedef __attribute__((ext_vector_type(2))) float v2f;
typedef unsigned long long ull;

__device__ __forceinline__ v2f v2fma(v2f a, v2f b, v2f c) {
#if defined(__has_builtin) && __has_builtin(__builtin_elementwise_fma)
  return __builtin_elementwise_fma(a, b, c);
#else
  v2f r; r.x = fmaf(a.x, b.x, c.x); r.y = fmaf(a.y, b.y, c.y); return r;
#endif
}

__device__ __forceinline__ float wave_reduce(float v) {
#pragma unroll
  for (int off = 32; off > 0; off >>= 1) v += __shfl_xor(v, off, 64);
  return v;
}
__device__ __forceinline__ ull wr64(ull v) {
#pragma unroll
  for (int off = 32; off > 0; off >>= 1) v += __shfl_xor(v, off, 64);
  return v;
}

// ---------------------------------------------------------------------------
// Pass 1: per-batch segment sums.
// R6: every non-spilling build so far ran with __launch_bounds__(.,4) and
// occupancy pinned at ~33-42% regardless of grid size, while the single
// (.,8) build hit 71% -> the 2nd arg empirically CAPS waves/EU here.
// Declare (256,8) and make the live set fit the 64-VGPR budget:
//  - counts packed in two u64s (8-bit fields, <=13 px/thread; expanded to
//    16-bit fields before wave-reduce, validated in R3),
//  - sums stay as 14 v2f (28 VGPR) -> v_pk_fma_f32,
//  - ILP=4, NO sched_barrier (forcing 28 load-dests live under a 64-reg
//    budget would guarantee scratch; R5 showed the compiler serializes
//    dest reuse anyway). Wave supply doubles: 16 -> 32 waves/CU.
// Tripwire: WRITE_SIZE >> 7 MB means it spilled after all -> drop ILP to 2.
// ---------------------------------------------------------------------------
__global__ __launch_bounds__(256, 8) void k_accum(
    const float4* __restrict__ emb, const int* __restrict__ inst,
    const float* __restrict__ ker, const float* __restrict__ tmk,
    float* __restrict__ acc, unsigned char* __restrict__ labc,
    int P, int use_cache)
{
  const int b = blockIdx.y;
  const size_t base = (size_t)b * P;
  const float4* e  = emb + base;
  const int*    ip = inst + base;
  const float*  kp = ker + base;
  const float*  tp = tmk + base;
  unsigned char* lb = labc + base;

  // s2[j][0]=(ch0,ch1), s2[j][1]=(ch2,ch3) for label j+1
  v2f s2[7][2];
#pragma unroll
  for (int j = 0; j < 7; ++j) { s2[j][0] = (v2f)(0.f); s2[j][1] = (v2f)(0.f); }
  ull ck64 = 0, ci64 = 0;     // 8-bit fields per label; max 13 px/thread

  const int T   = blockDim.x * gridDim.x;     // 32768 threads per batch row
  const int tid = blockIdx.x * blockDim.x + threadIdx.x;

  int p0 = tid;
  for (; p0 + (ILP - 1) * T < P; p0 += ILP * T) {
    int   iv[ILP]; float tv[ILP], kv[ILP]; float4 ev[ILP];
#pragma unroll
    for (int k = 0; k < ILP; ++k) iv[k] = ip[p0 + k * T];
#pragma unroll
    for (int k = 0; k < ILP; ++k) tv[k] = tp[p0 + k * T];
#pragma unroll
    for (int k = 0; k < ILP; ++k) kv[k] = kp[p0 + k * T];
#pragma unroll
    for (int k = 0; k < ILP; ++k) ev[k] = e[p0 + k * T];

#pragma unroll
    for (int k = 0; k < ILP; ++k) {
      int lab = (tv[k] > 0.5f) ? (iv[k] & 7) : 0;
      int ki  = (kv[k] > 0.5f) ? 1 : 0;
      float kf = (float)ki;
      if (use_cache) lb[p0 + k * T] = (unsigned char)lab;
      ci64 += 1ull << (8 * lab);
      ck64 += (ull)ki << (8 * lab);
#pragma unroll
      for (int l = 1; l < NLAB; ++l) {
        float mk = (lab == l) ? kf : 0.f;
        v2f mk2; mk2.x = mk; mk2.y = mk;
        v2f e01; e01.x = ev[k].x; e01.y = ev[k].y;
        v2f e23; e23.x = ev[k].z; e23.y = ev[k].w;
        s2[l - 1][0] = v2fma(mk2, e01, s2[l - 1][0]);
        s2[l - 1][1] = v2fma(mk2, e23, s2[l - 1][1]);
      }
    }
  }
  // scalar tail (<= ILP-1 pixels per thread)
  for (int p = p0; p < P; p += T) {
    int   iv = ip[p];
    float tv = tp[p];
    float kv = kp[p];
    float4 ev = e[p];
    int lab = (tv > 0.5f) ? (iv & 7) : 0;
    int ki  = (kv > 0.5f) ? 1 : 0;
    float kf = (float)ki;
    if (use_cache) lb[p] = (unsigned char)lab;
    ci64 += 1ull << (8 * lab);
    ck64 += (ull)ki << (8 * lab);
#pragma unroll
    for (int l = 1; l < NLAB; ++l) {
      float mk = (lab == l) ? kf : 0.f;
      v2f mk2; mk2.x = mk; mk2.y = mk;
      v2f e01; e01.x = ev.x; e01.y = ev.y;
      v2f e23; e23.x = ev.z; e23.y = ev.w;
      s2[l - 1][0] = v2fma(mk2, e01, s2[l - 1][0]);
      s2[l - 1][1] = v2fma(mk2, e23, s2[l - 1][1]);
    }
  }

  // block-level reduction: wave_reduce -> LDS -> one atomic per block per slot
  __shared__ float red[4][48];
  const int wid = threadIdx.x >> 6, lane = threadIdx.x & 63;
#pragma unroll
  for (int j = 0; j < 7; ++j) {
    float v0 = wave_reduce(s2[j][0].x);
    float v1 = wave_reduce(s2[j][0].y);
    float v2 = wave_reduce(s2[j][1].x);
    float v3 = wave_reduce(s2[j][1].y);
    if (lane == 0) {
      red[wid][S_OFF + j * 4 + 0] = v0;
      red[wid][S_OFF + j * 4 + 1] = v1;
      red[wid][S_OFF + j * 4 + 2] = v2;
      red[wid][S_OFF + j * 4 + 3] = v3;
    }
  }
  {
    // expand 8-bit fields to 16-bit (sum over 64 lanes <= 64*13 < 65536)
    const ull M8 = 0x00FF00FF00FF00FFull;
    ull ckA = wr64(ck64 & M8);          // labels 0,2,4,6 in 16-bit slots
    ull ckB = wr64((ck64 >> 8) & M8);   // labels 1,3,5,7
    ull ciA = wr64(ci64 & M8);
    ull ciB = wr64((ci64 >> 8) & M8);
    if (lane == 0) {
#pragma unroll
      for (int l = 1; l < NLAB; ++l) {
        ull v = (l & 1) ? (ckB >> (16 * (l >> 1))) : (ckA >> (16 * (l >> 1)));
        red[wid][CK_OFF + l - 1] = (float)(v & 0xFFFF);
      }
#pragma unroll
      for (int l = 2; l < NLAB; ++l) {
        ull v = (l & 1) ? (ciB >> (16 * (l >> 1))) : (ciA >> (16 * (l >> 1)));
        red[wid][CI_OFF + l - 2] = (float)(v & 0xFFFF);
      }
    }
  }
  __syncthreads();
  if (threadIdx.x < AG_OFF) {
    float v = red[0][threadIdx.x] + red[1][threadIdx.x] +
              red[2][threadIdx.x] + red[3][threadIdx.x];
    atomicAdd(acc + b * ACC_PER_B + threadIdx.x, v);
  }
}

// ---------------------------------------------------------------------------
// Pass 2: aggregation term vs mu, labels 2..7. (256,8), small live set
// (~45 VGPR), labels from the byte cache, emb L3-resident after pass 1.
// ---------------------------------------------------------------------------
__global__ __launch_bounds__(256, 8) void k_agg(
    const float4* __restrict__ emb, const int* __restrict__ inst,
    const float* __restrict__ tmk, const unsigned char* __restrict__ labc,
    float* __restrict__ acc, int P, int use_cache)
{
  const int b = blockIdx.y;
  const size_t base = (size_t)b * P;
  __shared__ float4 smu[NLAB];
  const float* accB = acc + b * ACC_PER_B;
  if (threadIdx.x < NLAB) {
    int l = threadIdx.x;
    float4 m;
    if (l == 0) {
      m = make_float4(0.f, 0.f, 0.f, 0.f);
    } else {
      float inv = 1.f / fmaxf(accB[CK_OFF + l - 1], 1.f);
      m = make_float4(accB[S_OFF + (l - 1) * 4 + 0] * inv,
                      accB[S_OFF + (l - 1) * 4 + 1] * inv,
                      accB[S_OFF + (l - 1) * 4 + 2] * inv,
                      accB[S_OFF + (l - 1) * 4 + 3] * inv);
    }
    smu[l] = m;
  }
  __syncthreads();

  const float4* e = emb + base;
  const unsigned char* lb = labc + base;
  const int*   ip = inst + base;
  const float* tp = tmk + base;

  float aggl[6];
#pragma unroll
  for (int l = 0; l < 6; ++l) aggl[l] = 0.f;

  const int T   = blockDim.x * gridDim.x;     // 32768 threads per batch row
  const int tid = blockIdx.x * blockDim.x + threadIdx.x;

  int p0 = tid;
  for (; p0 + (ILP - 1) * T < P; p0 += ILP * T) {
    int lab[ILP]; float4 ev[ILP];
    if (use_cache) {
#pragma unroll
      for (int k = 0; k < ILP; ++k) lab[k] = lb[p0 + k * T];
    } else {
      int iv[ILP]; float tv[ILP];
#pragma unroll
      for (int k = 0; k < ILP; ++k) iv[k] = ip[p0 + k * T];
#pragma unroll
      for (int k = 0; k < ILP; ++k) tv[k] = tp[p0 + k * T];
#pragma unroll
      for (int k = 0; k < ILP; ++k) lab[k] = (tv[k] > 0.5f) ? (iv[k] & 7) : 0;
    }
#pragma unroll
    for (int k = 0; k < ILP; ++k) ev[k] = e[p0 + k * T];

#pragma unroll
    for (int k = 0; k < ILP; ++k) {
      float4 mv = smu[lab[k]];
      float dx = ev[k].x - mv.x, dy = ev[k].y - mv.y;
      float dz = ev[k].z - mv.z, dw = ev[k].w - mv.w;
      float sq = dx * dx + dy * dy + dz * dz + dw * dw;
      float d  = sqrtf(sq);
      float t  = fmaxf(d - 0.5f, 0.f);                 // DELTA_V
      float term = (lab[k] >= 2) ? logf(fmaf(t, t, 1.f)) : 0.f;
#pragma unroll
      for (int l = 0; l < 6; ++l) aggl[l] += (lab[k] == l + 2) ? term : 0.f;
    }
  }
  for (int p = p0; p < P; p += T) {
    int lab;
    if (use_cache) lab = lb[p];
    else           lab = (tp[p] > 0.5f) ? (ip[p] & 7) : 0;
    float4 ev = e[p];
    float4 mv = smu[lab];
    float dx = ev.x - mv.x, dy = ev.y - mv.y;
    float dz = ev.z - mv.z, dw = ev.w - mv.w;
    float d = sqrtf(dx * dx + dy * dy + dz * dz + dw * dw);
    float t = fmaxf(d - 0.5f, 0.f);
    float term = (lab >= 2) ? logf(fmaf(t, t, 1.f)) : 0.f;
#pragma unroll
    for (int l = 0; l < 6; ++l) aggl[l] += (lab == l + 2) ? term : 0.f;
  }

  __shared__ float red[4][8];
  const int wid = threadIdx.x >> 6, lane = threadIdx.x & 63;
#pragma unroll
  for (int l = 0; l < 6; ++l) {
    float v = wave_reduce(aggl[l]);
    if (lane == 0) red[wid][l] = v;
  }
  __syncthreads();
  if (threadIdx.x < 6) {
    float v = red[0][threadIdx.x] + red[1][threadIdx.x] +
              red[2][threadIdx.x] + red[3][threadIdx.x];
    atomicAdd(acc + b * ACC_PER_B + AG_OFF + threadIdx.x, v);
  }
}

// ---------------------------------------------------------------------------
// Finalize: one wave; lane b handles batch b, then wave-reduce the batch mean.
// ---------------------------------------------------------------------------
__global__ void k_final(const float* __restrict__ acc, float* __restrict__ out, int nb) {
  const int lane = threadIdx.x;
  float loss = 0.f;
  if (lane < nb) {
    const float* a = acc + lane * ACC_PER_B;
    float mu[NLAB][4];
#pragma unroll
    for (int c = 0; c < 4; ++c) mu[0][c] = 0.f;
#pragma unroll
    for (int l = 1; l < NLAB; ++l) {
      float inv = 1.f / fmaxf(a[CK_OFF + l - 1], 1.f);
#pragma unroll
      for (int c = 0; c < 4; ++c) mu[l][c] = a[S_OFF + (l - 1) * 4 + c] * inv;
    }
    // l_agg = mean over labels 2..7 of agg_sum / max(cnt_i,1)
    float l_agg = 0.f;
#pragma unroll
    for (int l = 2; l < NLAB; ++l)
      l_agg += a[AG_OFF + l - 2] / fmaxf(a[CI_OFF + l - 2], 1.f);
    l_agg *= (1.f / 6.f);
    // l_dis over ordered pairs i!=j, i,j in 1..7 (42 pairs)
    float ssum = 0.f;
    for (int i = 1; i < NLAB; ++i)
      for (int j = 1; j < NLAB; ++j) {
        if (i == j) continue;
        float dx = mu[i][0] - mu[j][0], dy = mu[i][1] - mu[j][1];
        float dz = mu[i][2] - mu[j][2], dw = mu[i][3] - mu[j][3];
        float dd = sqrtf(dx * dx + dy * dy + dz * dz + dw * dw);
        float t = fmaxf(3.0f - dd, 0.f);         // 2*DELTA_D
        ssum += logf(fmaf(t, t, 1.f));
      }
    float l_dis = ssum / 42.f;
    // l_reg: mu[0]=0 contributes log(1)=0; mean over all 8 labels
    float rsum = 0.f;
#pragma unroll
    for (int l = 1; l < NLAB; ++l) {
      float n = sqrtf(mu[l][0] * mu[l][0] + mu[l][1] * mu[l][1] +
                      mu[l][2] * mu[l][2] + mu[l][3] * mu[l][3]);
      rsum += logf(n + 1.f);
    }
    float l_reg = rsum * (0.001f / NLAB);
    loss = l_agg + l_dis + l_reg;
  }
  loss = wave_reduce(loss);
  if (lane == 0) out[0] = loss / (float)nb;      // LOSS_WEIGHT = 1
}

extern "C" void kernel_launch(void* const* d_in, const int* in_sizes, int n_in,
                              void* d_out, int out_size, void* d_ws, size_t ws_size,
                              hipStream_t stream) {
  const float4* emb = (const float4*)d_in[0];
  const int*    inst = (const int*)d_in[1];
  const float*  ker  = (const float*)d_in[2];
  const float*  tmk  = (const float*)d_in[3];
  float* out = (float*)d_out;

  const int total = in_sizes[1];       // B*H*W
  const int P = total / BATCH;

  float* acc = (float*)d_ws;
  unsigned char* labc = (unsigned char*)((char*)d_ws + LAB_OFFSET);
  const size_t need = (size_t)LAB_OFFSET + (size_t)total;   // 1 byte per pixel
  const int use_cache = (ws_size >= need) ? 1 : 0;

  // d_ws is re-poisoned to 0xAA before every launch — zero the accumulators.
  hipMemsetAsync(d_ws, 0, ACC_FLOATS * sizeof(float), stream);

  k_accum<<<dim3(GX, BATCH), 256, 0, stream>>>(emb, inst, ker, tmk, acc, labc, P, use_cache);
  k_agg  <<<dim3(GX, BATCH), 256, 0, stream>>>(emb, inst, tmk, labc, acc, P, use_cache);
  k_final<<<1, 64, 0, stream>>>(acc, out, BATCH);
}

// Round 7
// 243.775 us; speedup vs baseline: 1.0460x; 1.0460x over previous
//
#include <hip/hip_runtime.h>
#include <math.h>

#define NLAB 8
#define BATCH 16
// acc layout per batch (floats):
//   [0..27]  emb sums, labels 1..7 x 4 ch
//   [28..34] cnt_k, labels 1..7
//   [35..40] cnt_i, labels 2..7
//   [41..46] agg sums, labels 2..7
#define S_OFF  0
#define CK_OFF 28
#define CI_OFF 35
#define AG_OFF 41
#define ACC_PER_B 48
#define ACC_FLOATS (BATCH * ACC_PER_B)
#define LAB_OFFSET 4096              // label byte-cache starts here in d_ws
#define GX 128                       // 128x16 = 2048 blocks = 8 blocks/CU offered
#define TSPAN (GX * 256)             // compile-time thread span per batch row
#define ILP 4

typedef __attribute__((ext_vector_type(2))) float v2f;
typedef unsigned long long ull;

__device__ __forceinline__ v2f v2fma(v2f a, v2f b, v2f c) {
#if defined(__has_builtin) && __has_builtin(__builtin_elementwise_fma)
  return __builtin_elementwise_fma(a, b, c);
#else
  v2f r; r.x = fmaf(a.x, b.x, c.x); r.y = fmaf(a.y, b.y, c.y); return r;
#endif
}

__device__ __forceinline__ float wave_reduce(float v) {
#pragma unroll
  for (int off = 32; off > 0; off >>= 1) v += __shfl_xor(v, off, 64);
  return v;
}
__device__ __forceinline__ ull wr64(ull v) {
#pragma unroll
  for (int off = 32; off > 0; off >>= 1) v += __shfl_xor(v, off, 64);
  return v;
}

// ---------------------------------------------------------------------------
// Pass 1: per-batch segment sums.
// R7: the 2nd __launch_bounds__ arg is toxic on this toolchain:
//   (.,4) -> amdgpu-waves-per-eu=4 caps HW occupancy at 50% (observed <=42%),
//   (.,8) -> compiler pins VGPR=32 and spills 45-130 MB (R2, R6).
// Drop it. Natural allocation for this body is ~50-60 VGPR (every non-spill
// build: 44-60); at VGPR<=64 hardware allows 8 waves/SIMD (occupancy steps
// at 64/128/256). Live set kept small: u64-packed counts (8-bit fields,
// <=13 px/thread, expanded to 16-bit pre-reduce — validated R6), v2f sums
// (v_pk_fma_f32), ILP=4, compile-time TSPAN.
// ---------------------------------------------------------------------------
__global__ __launch_bounds__(256) void k_accum(
    const float4* __restrict__ emb, const int* __restrict__ inst,
    const float* __restrict__ ker, const float* __restrict__ tmk,
    float* __restrict__ acc, unsigned char* __restrict__ labc,
    int P, int use_cache)
{
  const int b = blockIdx.y;
  const size_t base = (size_t)b * P;
  const float4* e  = emb + base;
  const int*    ip = inst + base;
  const float*  kp = ker + base;
  const float*  tp = tmk + base;
  unsigned char* lb = labc + base;

  // s2[j][0]=(ch0,ch1), s2[j][1]=(ch2,ch3) for label j+1
  v2f s2[7][2];
#pragma unroll
  for (int j = 0; j < 7; ++j) { s2[j][0] = (v2f)(0.f); s2[j][1] = (v2f)(0.f); }
  ull ck64 = 0, ci64 = 0;     // 8-bit fields per label; max 13 px/thread

  const int tid = blockIdx.x * blockDim.x + threadIdx.x;

  int p0 = tid;
  for (; p0 + (ILP - 1) * TSPAN < P; p0 += ILP * TSPAN) {
    int   iv[ILP]; float tv[ILP], kv[ILP]; float4 ev[ILP];
#pragma unroll
    for (int k = 0; k < ILP; ++k) iv[k] = ip[p0 + k * TSPAN];
#pragma unroll
    for (int k = 0; k < ILP; ++k) tv[k] = tp[p0 + k * TSPAN];
#pragma unroll
    for (int k = 0; k < ILP; ++k) kv[k] = kp[p0 + k * TSPAN];
#pragma unroll
    for (int k = 0; k < ILP; ++k) ev[k] = e[p0 + k * TSPAN];

#pragma unroll
    for (int k = 0; k < ILP; ++k) {
      int lab = (tv[k] > 0.5f) ? (iv[k] & 7) : 0;
      int ki  = (kv[k] > 0.5f) ? 1 : 0;
      float kf = (float)ki;
      if (use_cache) lb[p0 + k * TSPAN] = (unsigned char)lab;
      ci64 += 1ull << (8 * lab);
      ck64 += (ull)ki << (8 * lab);
#pragma unroll
      for (int l = 1; l < NLAB; ++l) {
        float mk = (lab == l) ? kf : 0.f;
        v2f mk2; mk2.x = mk; mk2.y = mk;
        v2f e01; e01.x = ev[k].x; e01.y = ev[k].y;
        v2f e23; e23.x = ev[k].z; e23.y = ev[k].w;
        s2[l - 1][0] = v2fma(mk2, e01, s2[l - 1][0]);
        s2[l - 1][1] = v2fma(mk2, e23, s2[l - 1][1]);
      }
    }
  }
  // scalar tail (<= ILP-1 pixels per thread)
  for (int p = p0; p < P; p += TSPAN) {
    int   iv = ip[p];
    float tv = tp[p];
    float kv = kp[p];
    float4 ev = e[p];
    int lab = (tv > 0.5f) ? (iv & 7) : 0;
    int ki  = (kv > 0.5f) ? 1 : 0;
    float kf = (float)ki;
    if (use_cache) lb[p] = (unsigned char)lab;
    ci64 += 1ull << (8 * lab);
    ck64 += (ull)ki << (8 * lab);
#pragma unroll
    for (int l = 1; l < NLAB; ++l) {
      float mk = (lab == l) ? kf : 0.f;
      v2f mk2; mk2.x = mk; mk2.y = mk;
      v2f e01; e01.x = ev.x; e01.y = ev.y;
      v2f e23; e23.x = ev.z; e23.y = ev.w;
      s2[l - 1][0] = v2fma(mk2, e01, s2[l - 1][0]);
      s2[l - 1][1] = v2fma(mk2, e23, s2[l - 1][1]);
    }
  }

  // block-level reduction: wave_reduce -> LDS -> one atomic per block per slot
  __shared__ float red[4][48];
  const int wid = threadIdx.x >> 6, lane = threadIdx.x & 63;
#pragma unroll
  for (int j = 0; j < 7; ++j) {
    float v0 = wave_reduce(s2[j][0].x);
    float v1 = wave_reduce(s2[j][0].y);
    float v2 = wave_reduce(s2[j][1].x);
    float v3 = wave_reduce(s2[j][1].y);
    if (lane == 0) {
      red[wid][S_OFF + j * 4 + 0] = v0;
      red[wid][S_OFF + j * 4 + 1] = v1;
      red[wid][S_OFF + j * 4 + 2] = v2;
      red[wid][S_OFF + j * 4 + 3] = v3;
    }
  }
  {
    // expand 8-bit fields to 16-bit (sum over 64 lanes <= 64*13 < 65536)
    const ull M8 = 0x00FF00FF00FF00FFull;
    ull ckA = wr64(ck64 & M8);          // labels 0,2,4,6 in 16-bit slots
    ull ckB = wr64((ck64 >> 8) & M8);   // labels 1,3,5,7
    ull ciA = wr64(ci64 & M8);
    ull ciB = wr64((ci64 >> 8) & M8);
    if (lane == 0) {
#pragma unroll
      for (int l = 1; l < NLAB; ++l) {
        ull v = (l & 1) ? (ckB >> (16 * (l >> 1))) : (ckA >> (16 * (l >> 1)));
        red[wid][CK_OFF + l - 1] = (float)(v & 0xFFFF);
      }
#pragma unroll
      for (int l = 2; l < NLAB; ++l) {
        ull v = (l & 1) ? (ciB >> (16 * (l >> 1))) : (ciA >> (16 * (l >> 1)));
        red[wid][CI_OFF + l - 2] = (float)(v & 0xFFFF);
      }
    }
  }
  __syncthreads();
  if (threadIdx.x < AG_OFF) {
    float v = red[0][threadIdx.x] + red[1][threadIdx.x] +
              red[2][threadIdx.x] + red[3][threadIdx.x];
    atomicAdd(acc + b * ACC_PER_B + threadIdx.x, v);
  }
}

// ---------------------------------------------------------------------------
// Pass 2: aggregation term vs mu, labels 2..7. Same no-min-waves annotation;
// small live set (~45 VGPR), labels from byte cache, emb L3-resident.
// ---------------------------------------------------------------------------
__global__ __launch_bounds__(256) void k_agg(
    const float4* __restrict__ emb, const int* __restrict__ inst,
    const float* __restrict__ tmk, const unsigned char* __restrict__ labc,
    float* __restrict__ acc, int P, int use_cache)
{
  const int b = blockIdx.y;
  const size_t base = (size_t)b * P;
  __shared__ float4 smu[NLAB];
  const float* accB = acc + b * ACC_PER_B;
  if (threadIdx.x < NLAB) {
    int l = threadIdx.x;
    float4 m;
    if (l == 0) {
      m = make_float4(0.f, 0.f, 0.f, 0.f);
    } else {
      float inv = 1.f / fmaxf(accB[CK_OFF + l - 1], 1.f);
      m = make_float4(accB[S_OFF + (l - 1) * 4 + 0] * inv,
                      accB[S_OFF + (l - 1) * 4 + 1] * inv,
                      accB[S_OFF + (l - 1) * 4 + 2] * inv,
                      accB[S_OFF + (l - 1) * 4 + 3] * inv);
    }
    smu[l] = m;
  }
  __syncthreads();

  const float4* e = emb + base;
  const unsigned char* lb = labc + base;
  const int*   ip = inst + base;
  const float* tp = tmk + base;

  float aggl[6];
#pragma unroll
  for (int l = 0; l < 6; ++l) aggl[l] = 0.f;

  const int tid = blockIdx.x * blockDim.x + threadIdx.x;

  int p0 = tid;
  for (; p0 + (ILP - 1) * TSPAN < P; p0 += ILP * TSPAN) {
    int lab[ILP]; float4 ev[ILP];
    if (use_cache) {
#pragma unroll
      for (int k = 0; k < ILP; ++k) lab[k] = lb[p0 + k * TSPAN];
    } else {
      int iv[ILP]; float tv[ILP];
#pragma unroll
      for (int k = 0; k < ILP; ++k) iv[k] = ip[p0 + k * TSPAN];
#pragma unroll
      for (int k = 0; k < ILP; ++k) tv[k] = tp[p0 + k * TSPAN];
#pragma unroll
      for (int k = 0; k < ILP; ++k) lab[k] = (tv[k] > 0.5f) ? (iv[k] & 7) : 0;
    }
#pragma unroll
    for (int k = 0; k < ILP; ++k) ev[k] = e[p0 + k * TSPAN];

#pragma unroll
    for (int k = 0; k < ILP; ++k) {
      float4 mv = smu[lab[k]];
      float dx = ev[k].x - mv.x, dy = ev[k].y - mv.y;
      float dz = ev[k].z - mv.z, dw = ev[k].w - mv.w;
      float sq = dx * dx + dy * dy + dz * dz + dw * dw;
      float d  = sqrtf(sq);
      float t  = fmaxf(d - 0.5f, 0.f);                 // DELTA_V
      float term = (lab[k] >= 2) ? logf(fmaf(t, t, 1.f)) : 0.f;
#pragma unroll
      for (int l = 0; l < 6; ++l) aggl[l] += (lab[k] == l + 2) ? term : 0.f;
    }
  }
  for (int p = p0; p < P; p += TSPAN) {
    int lab;
    if (use_cache) lab = lb[p];
    else           lab = (tp[p] > 0.5f) ? (ip[p] & 7) : 0;
    float4 ev = e[p];
    float4 mv = smu[lab];
    float dx = ev.x - mv.x, dy = ev.y - mv.y;
    float dz = ev.z - mv.z, dw = ev.w - mv.w;
    float d = sqrtf(dx * dx + dy * dy + dz * dz + dw * dw);
    float t = fmaxf(d - 0.5f, 0.f);
    float term = (lab >= 2) ? logf(fmaf(t, t, 1.f)) : 0.f;
#pragma unroll
    for (int l = 0; l < 6; ++l) aggl[l] += (lab == l + 2) ? term : 0.f;
  }

  __shared__ float red[4][8];
  const int wid = threadIdx.x >> 6, lane = threadIdx.x & 63;
#pragma unroll
  for (int l = 0; l < 6; ++l) {
    float v = wave_reduce(aggl[l]);
    if (lane == 0) red[wid][l] = v;
  }
  __syncthreads();
  if (threadIdx.x < 6) {
    float v = red[0][threadIdx.x] + red[1][threadIdx.x] +
              red[2][threadIdx.x] + red[3][threadIdx.x];
    atomicAdd(acc + b * ACC_PER_B + AG_OFF + threadIdx.x, v);
  }
}

// ---------------------------------------------------------------------------
// Finalize: one wave; lane b handles batch b, then wave-reduce the batch mean.
// ---------------------------------------------------------------------------
__global__ void k_final(const float* __restrict__ acc, float* __restrict__ out, int nb) {
  const int lane = threadIdx.x;
  float loss = 0.f;
  if (lane < nb) {
    const float* a = acc + lane * ACC_PER_B;
    float mu[NLAB][4];
#pragma unroll
    for (int c = 0; c < 4; ++c) mu[0][c] = 0.f;
#pragma unroll
    for (int l = 1; l < NLAB; ++l) {
      float inv = 1.f / fmaxf(a[CK_OFF + l - 1], 1.f);
#pragma unroll
      for (int c = 0; c < 4; ++c) mu[l][c] = a[S_OFF + (l - 1) * 4 + c] * inv;
    }
    // l_agg = mean over labels 2..7 of agg_sum / max(cnt_i,1)
    float l_agg = 0.f;
#pragma unroll
    for (int l = 2; l < NLAB; ++l)
      l_agg += a[AG_OFF + l - 2] / fmaxf(a[CI_OFF + l - 2], 1.f);
    l_agg *= (1.f / 6.f);
    // l_dis over ordered pairs i!=j, i,j in 1..7 (42 pairs)
    float ssum = 0.f;
    for (int i = 1; i < NLAB; ++i)
      for (int j = 1; j < NLAB; ++j) {
        if (i == j) continue;
        float dx = mu[i][0] - mu[j][0], dy = mu[i][1] - mu[j][1];
        float dz = mu[i][2] - mu[j][2], dw = mu[i][3] - mu[j][3];
        float dd = sqrtf(dx * dx + dy * dy + dz * dz + dw * dw);
        float t = fmaxf(3.0f - dd, 0.f);         // 2*DELTA_D
        ssum += logf(fmaf(t, t, 1.f));
      }
    float l_dis = ssum / 42.f;
    // l_reg: mu[0]=0 contributes log(1)=0; mean over all 8 labels
    float rsum = 0.f;
#pragma unroll
    for (int l = 1; l < NLAB; ++l) {
      float n = sqrtf(mu[l][0] * mu[l][0] + mu[l][1] * mu[l][1] +
                      mu[l][2] * mu[l][2] + mu[l][3] * mu[l][3]);
      rsum += logf(n + 1.f);
    }
    float l_reg = rsum * (0.001f / NLAB);
    loss = l_agg + l_dis + l_reg;
  }
  loss = wave_reduce(loss);
  if (lane == 0) out[0] = loss / (float)nb;      // LOSS_WEIGHT = 1
}

extern "C" void kernel_launch(void* const* d_in, const int* in_sizes, int n_in,
                              void* d_out, int out_size, void* d_ws, size_t ws_size,
                              hipStream_t stream) {
  const float4* emb = (const float4*)d_in[0];
  const int*    inst = (const int*)d_in[1];
  const float*  ker  = (const float*)d_in[2];
  const float*  tmk  = (const float*)d_in[3];
  float* out = (float*)d_out;

  const int total = in_sizes[1];       // B*H*W
  const int P = total / BATCH;

  float* acc = (float*)d_ws;
  unsigned char* labc = (unsigned char*)((char*)d_ws + LAB_OFFSET);
  const size_t need = (size_t)LAB_OFFSET + (size_t)total;   // 1 byte per pixel
  const int use_cache = (ws_size >= need) ? 1 : 0;

  // d_ws is re-poisoned to 0xAA before every launch — zero the accumulators.
  hipMemsetAsync(d_ws, 0, ACC_FLOATS * sizeof(float), stream);

  k_accum<<<dim3(GX, BATCH), 256, 0, stream>>>(emb, inst, ker, tmk, acc, labc, P, use_cache);
  k_agg  <<<dim3(GX, BATCH), 256, 0, stream>>>(emb, inst, tmk, labc, acc, P, use_cache);
  k_final<<<1, 64, 0, stream>>>(acc, out, BATCH);
}